// Round 7
// baseline (847.202 us; speedup 1.0000x reference)
//
#include <hip/hip_runtime.h>

// ---------------- problem constants (fixed by reference) ----------------
#define N_NODES 100000
#define N_EDGES 1600000
#define NG      512
#define NPART   8          // dst partitions (bucket radix)
#define NPP     12500      // nodes per partition
#define BCAP    245760     // per-bucket capacity (entries; expected ~200K)
#define BQ      1024       // LDS staging entries per bucket
#define BFLUSH  512        // flush chunk
#define NBBLK   256        // k_bin blocks
#define EPB     ((N_EDGES + NBBLK - 1) / NBBLK)   // 6250 edges per bin-block

static __device__ __forceinline__ float lrelu(float v) {
    return v >= 0.0f ? v : 0.01f * v;
}

// ---------------- tiny setup kernels ----------------
__global__ void k_zero_i32(int* __restrict__ p, int n) {
    int i = blockIdx.x * blockDim.x + threadIdx.x;
    if (i < n) p[i] = 0;
}

__global__ void k_copy_i32(const int* __restrict__ s, int* __restrict__ d, int n) {
    int i = blockIdx.x * blockDim.x + threadIdx.x;
    if (i < n) d[i] = s[i];
}

// dinv = 1/sqrt(deg+1); dinv2 = 1/(deg+1); sdeg = sqrt(deg+1)
__global__ void k_dinv(const int* __restrict__ counts, float* __restrict__ dinv,
                       float* __restrict__ dinv2, float* __restrict__ sdeg) {
    int i = blockIdx.x * blockDim.x + threadIdx.x;
    if (i < N_NODES) {
        float deg = (float)(counts[i] + 1);
        float s = sqrtf(deg);
        sdeg[i] = s;
        dinv[i] = 1.0f / s;
        dinv2[i] = 1.0f / deg;
    }
}

// ---------------- phase A: bin edges into 8 dst-partition buckets ----------------
// LDS-staged, coalesced 4KB chunk flushes via per-bucket global cursors.
__global__ __launch_bounds__(256) void k_bin(const int* __restrict__ esrc,
                                             const int* __restrict__ edst,
                                             int* __restrict__ gcur,
                                             uint2* __restrict__ gbuf) {
    __shared__ uint2 buf[NPART][BQ];
    __shared__ int lcnt[NPART];
    __shared__ int gbase[NPART];
    if (threadIdx.x < NPART) lcnt[threadIdx.x] = 0;
    __syncthreads();
    int base = blockIdx.x * EPB;
    int end = base + EPB; if (end > N_EDGES) end = N_EDGES;
    for (int r = base; r < end; r += 2048) {
        int rend = r + 2048; if (rend > end) rend = end;
        for (int e = r + (int)threadIdx.x; e < rend; e += 256) {
            int d = edst[e];
            int s = esrc[e];
            int b = d / NPP;                      // 0..7 (magic-mul)
            int pos = atomicAdd(&lcnt[b], 1);
            if (pos < BQ) {
                buf[b][pos] = make_uint2((unsigned)s, (unsigned)d);
            } else {                              // never taken for uniform input; safety
                int g = atomicAdd(&gcur[b], 1);
                gbuf[(size_t)b * BCAP + g] = make_uint2((unsigned)s, (unsigned)d);
            }
        }
        __syncthreads();
        for (int b = 0; b < NPART; ++b) {
            int cnt = lcnt[b];
            if (cnt >= BFLUSH) {
                if (threadIdx.x == 0) gbase[b] = atomicAdd(&gcur[b], BFLUSH);
                __syncthreads();
                int gb = gbase[b];
                for (int i = threadIdx.x; i < BFLUSH; i += 256)
                    gbuf[(size_t)b * BCAP + gb + i] = buf[b][i];
                __syncthreads();
                int inb = cnt < BQ ? cnt : BQ;
                int rem = inb - BFLUSH;           // <= 512: src region disjoint from dst
                for (int i = threadIdx.x; i < rem; i += 256)
                    buf[b][i] = buf[b][BFLUSH + i];
                __syncthreads();
                if (threadIdx.x == 0) lcnt[b] = rem;
                __syncthreads();
            }
        }
    }
    // final drain
    for (int b = 0; b < NPART; ++b) {
        int cnt = lcnt[b]; if (cnt > BQ) cnt = BQ;
        if (cnt > 0) {
            if (threadIdx.x == 0) gbase[b] = atomicAdd(&gcur[b], cnt);
            __syncthreads();
            int gb = gbase[b];
            for (int i = threadIdx.x; i < cnt; i += 256)
                gbuf[(size_t)b * BCAP + gb + i] = buf[b][i];
        }
        __syncthreads();
    }
}

// ---------------- phase B1: per-partition degree count via LDS histogram ---------
__global__ __launch_bounds__(1024) void k_count_b(const int* __restrict__ gcur,
                                                  const uint2* __restrict__ gbuf,
                                                  int* __restrict__ counts) {
    __shared__ int h[NPP];
    int p = blockIdx.x & (NPART - 1);
    int slice = blockIdx.x >> 3;                  // 0..7
    for (int i = threadIdx.x; i < NPP; i += 1024) h[i] = 0;
    __syncthreads();
    int n = gcur[p];
    int per = (n + 7) / 8;
    int lo = slice * per, hi = lo + per; if (hi > n) hi = n;
    const uint2* bb = gbuf + (size_t)p * BCAP;
    int pl = p * NPP;
    for (int i = lo + (int)threadIdx.x; i < hi; i += 1024) {
        int d = (int)bb[i].y - pl;
        atomicAdd(&h[d], 1);
    }
    __syncthreads();
    for (int i = threadIdx.x; i < NPP; i += 1024)
        if (h[i]) atomicAdd(&counts[pl + i], h[i]);
}

// ---------------- exclusive scan (counts -> offsets) ----------------
__global__ void k_scan_block(const int* __restrict__ counts, int* __restrict__ offsets,
                             int* __restrict__ bsums, int n) {
    __shared__ int tmp[1024];
    int gid = blockIdx.x * 1024 + threadIdx.x;
    int v = (gid < n) ? counts[gid] : 0;
    tmp[threadIdx.x] = v;
    __syncthreads();
    for (int off = 1; off < 1024; off <<= 1) {
        int t = (threadIdx.x >= off) ? tmp[threadIdx.x - off] : 0;
        __syncthreads();
        tmp[threadIdx.x] += t;
        __syncthreads();
    }
    if (gid < n) offsets[gid + 1] = tmp[threadIdx.x];
    if (threadIdx.x == 1023) bsums[blockIdx.x] = tmp[1023];
}

__global__ void k_scan_bsums(int* __restrict__ bsums, int nb) {
    if (blockIdx.x == 0 && threadIdx.x == 0) {
        int acc = 0;
        for (int b = 0; b < nb; ++b) { int v = bsums[b]; bsums[b] = acc; acc += v; }
    }
}

__global__ void k_scan_add(int* __restrict__ offsets, const int* __restrict__ bsums, int n) {
    int gid = blockIdx.x * 1024 + threadIdx.x;
    if (gid < n) offsets[gid + 1] += bsums[blockIdx.x];
    if (gid == 0) offsets[0] = 0;
}

// ---------------- phase B2: per-partition CSR scatter from bucket ----------------
// stream is partition-local (1.6MB) so csr lines stay L2-hot -> single writeback
__global__ __launch_bounds__(256) void k_scatter_b(const int* __restrict__ gcur,
                                                   const uint2* __restrict__ gbuf,
                                                   int* __restrict__ cursor,
                                                   int* __restrict__ csr_src) {
    int p = blockIdx.x & (NPART - 1);
    int slice = blockIdx.x >> 3;                  // 0..15
    int n = gcur[p];
    int per = (n + 15) / 16;
    int lo = slice * per, hi = lo + per; if (hi > n) hi = n;
    const uint2* bb = gbuf + (size_t)p * BCAP;
    for (int i = lo + (int)threadIdx.x; i < hi; i += 256) {
        uint2 e = bb[i];
        int pos = atomicAdd(&cursor[e.y], 1);
        csr_src[pos] = (int)e.x;
    }
}

// ---------------- v-space init: v = dinv .* x, padded to float4 ----------------
__global__ void k_vinit(const float* __restrict__ x, const float* __restrict__ dinv,
                        float4* __restrict__ v) {
    int i = blockIdx.x * blockDim.x + threadIdx.x;
    if (i >= N_NODES) return;
    float di = dinv[i];
    v[i] = make_float4(di * x[i * 3 + 0], di * x[i * 3 + 1], di * x[i * 3 + 2], 0.0f);
}

// ---------------- diffusion (v-space): v' = 0.5*(v + dinv2*(sum_nbr + v)) --------
// pass 1: float4 node state, 8 edge-split lanes per node -> 800K threads
__global__ __launch_bounds__(256) void k_vdiff3(
    const float4* __restrict__ xin, float4* __restrict__ xout,
    const int* __restrict__ offs, const int* __restrict__ csrc,
    const float* __restrict__ dinv2) {
    int t = blockIdx.x * 256 + threadIdx.x;
    if (t >= N_NODES * 8) return;
    int h = t & 7;
    int i = t >> 3;
    int b = offs[i], e = offs[i + 1];
    float a0 = 0.0f, a1 = 0.0f, a2 = 0.0f;
    for (int p = b + h; p < e; p += 8) {
        int s = csrc[p];
        float4 xv = xin[s];
        a0 += xv.x; a1 += xv.y; a2 += xv.z;
    }
    a0 += __shfl_xor(a0, 1, 64); a1 += __shfl_xor(a1, 1, 64); a2 += __shfl_xor(a2, 1, 64);
    a0 += __shfl_xor(a0, 2, 64); a1 += __shfl_xor(a1, 2, 64); a2 += __shfl_xor(a2, 2, 64);
    a0 += __shfl_xor(a0, 4, 64); a1 += __shfl_xor(a1, 4, 64); a2 += __shfl_xor(a2, 4, 64);
    if (h == 0) {
        float d2 = dinv2[i];
        float4 sv = xin[i];
        xout[i] = make_float4(0.5f * (sv.x + d2 * (a0 + sv.x)),
                              0.5f * (sv.y + d2 * (a1 + sv.y)),
                              0.5f * (sv.z + d2 * (a2 + sv.z)), 0.0f);
    }
}

// pass 2: 12 lanes/node = (3 quads x 4 edge-split) -> 1.2M threads, 1 float4/edge-iter
__global__ __launch_bounds__(256) void k_vdiff12(
    const float4* __restrict__ xin, float4* __restrict__ xout,
    const int* __restrict__ offs, const int* __restrict__ csrc,
    const float* __restrict__ dinv2) {
    int t = blockIdx.x * 256 + threadIdx.x;
    if (t >= N_NODES * 12) return;
    int i = t / 12;
    int r = t % 12;
    int q = r >> 2;        // quad 0..2
    int h = r & 3;         // edge-split lane 0..3 (consecutive lanes)
    int b = offs[i], e = offs[i + 1];
    float ax = 0.0f, ay = 0.0f, az = 0.0f, aw = 0.0f;
    for (int p = b + h; p < e; p += 4) {
        int s = csrc[p];
        float4 xv = xin[s * 3 + q];
        ax += xv.x; ay += xv.y; az += xv.z; aw += xv.w;
    }
    ax += __shfl_xor(ax, 1, 64); ay += __shfl_xor(ay, 1, 64);
    az += __shfl_xor(az, 1, 64); aw += __shfl_xor(aw, 1, 64);
    ax += __shfl_xor(ax, 2, 64); ay += __shfl_xor(ay, 2, 64);
    az += __shfl_xor(az, 2, 64); aw += __shfl_xor(aw, 2, 64);
    if (h == 0) {
        float d2 = dinv2[i];
        float4 sv = xin[i * 3 + q];
        xout[i * 3 + q] = make_float4(0.5f * (sv.x + d2 * (ax + sv.x)),
                                      0.5f * (sv.y + d2 * (ay + sv.y)),
                                      0.5f * (sv.z + d2 * (az + sv.z)),
                                      0.5f * (sv.w + d2 * (aw + sv.w)));
    }
}

// ---------------- s1 in v-space: |vL[f]-vL[f+1]| (float4-padded levels in) -------
__global__ void k_s1v(const float4* __restrict__ L1, const float4* __restrict__ L2,
                      const float4* __restrict__ L4, const float4* __restrict__ L8,
                      const float4* __restrict__ L16, float* __restrict__ s1v) {
    int i = blockIdx.x * blockDim.x + threadIdx.x;
    if (i >= N_NODES) return;
    float4 v[5];
    v[0] = L1[i]; v[1] = L2[i]; v[2] = L4[i]; v[3] = L8[i]; v[4] = L16[i];
    float* out = s1v + (size_t)i * 12;
#pragma unroll
    for (int f = 0; f < 4; ++f) {
        out[0 * 4 + f] = fabsf(v[f].x - v[f + 1].x);
        out[1 * 4 + f] = fabsf(v[f].y - v[f + 1].y);
        out[2 * 4 + f] = fabsf(v[f].z - v[f + 1].z);
    }
}

// ---------------- feats (N,33), converting v-space -> x-space via sdeg -----------
__global__ void k_feats(const float* __restrict__ x, const float* __restrict__ s1v,
                        const float* __restrict__ M1, const float* __restrict__ M2,
                        const float* __restrict__ M4, const float* __restrict__ M8,
                        const float* __restrict__ M16, const float* __restrict__ sdeg,
                        float* __restrict__ feats) {
    int i = blockIdx.x * blockDim.x + threadIdx.x;
    if (i >= N_NODES) return;
    float sd = sdeg[i];
    float* out = feats + (size_t)i * 33;
    out[0] = x[i * 3 + 0];
    out[1] = x[i * 3 + 1];
    out[2] = x[i * 3 + 2];
    for (int r = 1; r <= 4; ++r)
        for (int c = 0; c < 3; ++c)
            out[r * 3 + c] = sd * s1v[(size_t)i * 12 + c * 4 + (r - 1)];
    const float* Ms[5] = {M1, M2, M4, M8, M16};
    const int FENG[6] = {4, 8, 9, 12, 13, 14};
    for (int m = 0; m < 6; ++m) {
        for (int c2 = 0; c2 < 3; ++c2) {
            int idx = c2 * 16 + FENG[m];
            int w = idx / 12, rem = idx % 12, cc = rem / 4, f = rem % 4;
            float v = Ms[w][(size_t)i * 12 + cc * 4 + f] - Ms[w + 1][(size_t)i * 12 + cc * 4 + f];
            out[(5 + m) * 3 + c2] = fabsf(sd * v);
        }
    }
}

// ---------------- per-graph moments (batch sorted -> binary search range) --------
static __device__ __forceinline__ int lower_bound_i(const int* __restrict__ a, int n, int key) {
    int lo = 0, hi = n;
    while (lo < hi) { int mid = (lo + hi) >> 1; if (a[mid] < key) lo = mid + 1; else hi = mid; }
    return lo;
}

__global__ __launch_bounds__(256) void k_moments_mean(
    const float* __restrict__ feats, const int* __restrict__ batch,
    float* __restrict__ meanbuf) {
    __shared__ float part[4][33];
    int g = blockIdx.x;
    int lo = lower_bound_i(batch, N_NODES, g);
    int hi = lower_bound_i(batch, N_NODES, g + 1);
    float acc[33];
#pragma unroll
    for (int c = 0; c < 33; ++c) acc[c] = 0.0f;
    for (int i = lo + (int)threadIdx.x; i < hi; i += 256) {
        const float* f = feats + (size_t)i * 33;
#pragma unroll
        for (int c = 0; c < 33; ++c) acc[c] += f[c];
    }
#pragma unroll
    for (int c = 0; c < 33; ++c) {
        float v = acc[c];
        for (int o = 32; o >= 1; o >>= 1) v += __shfl_down(v, o, 64);
        acc[c] = v;
    }
    int wid = threadIdx.x >> 6, lane = threadIdx.x & 63;
    if (lane == 0)
        for (int c = 0; c < 33; ++c) part[wid][c] = acc[c];
    __syncthreads();
    if (threadIdx.x < 33) {
        float cnt = (float)((hi - lo) > 1 ? (hi - lo) : 1);
        float s = part[0][threadIdx.x] + part[1][threadIdx.x] +
                  part[2][threadIdx.x] + part[3][threadIdx.x];
        meanbuf[g * 33 + threadIdx.x] = s / cnt;
    }
}

__global__ __launch_bounds__(256) void k_moments_vs(
    const float* __restrict__ feats, const int* __restrict__ batch,
    const float* __restrict__ meanbuf, float* __restrict__ h0) {
    __shared__ float part2[4][33];
    __shared__ float part3[4][33];
    int g = blockIdx.x;
    int lo = lower_bound_i(batch, N_NODES, g);
    int hi = lower_bound_i(batch, N_NODES, g + 1);
    float mu[33], a2[33], a3[33];
#pragma unroll
    for (int c = 0; c < 33; ++c) { mu[c] = meanbuf[g * 33 + c]; a2[c] = 0.0f; a3[c] = 0.0f; }
    for (int i = lo + (int)threadIdx.x; i < hi; i += 256) {
        const float* f = feats + (size_t)i * 33;
#pragma unroll
        for (int c = 0; c < 33; ++c) {
            float d = f[c] - mu[c];
            float d2 = d * d;
            a2[c] += d2;
            a3[c] += d2 * d;
        }
    }
#pragma unroll
    for (int c = 0; c < 33; ++c) {
        float v2 = a2[c], v3 = a3[c];
        for (int o = 32; o >= 1; o >>= 1) {
            v2 += __shfl_down(v2, o, 64);
            v3 += __shfl_down(v3, o, 64);
        }
        a2[c] = v2; a3[c] = v3;
    }
    int wid = threadIdx.x >> 6, lane = threadIdx.x & 63;
    if (lane == 0)
        for (int c = 0; c < 33; ++c) { part2[wid][c] = a2[c]; part3[wid][c] = a3[c]; }
    __syncthreads();
    if (threadIdx.x < 33) {
        int c = threadIdx.x;
        float cnt = (float)((hi - lo) > 1 ? (hi - lo) : 1);
        float v2 = part2[0][c] + part2[1][c] + part2[2][c] + part2[3][c];
        float v3 = part3[0][c] + part3[1][c] + part3[2][c] + part3[3][c];
        h0[g * 99 + c]      = lrelu(mu[c]);
        h0[g * 99 + 33 + c] = lrelu(v2 / cnt);
        h0[g * 99 + 66 + c] = lrelu(v3 / cnt);
    }
}

// ---------------- fused per-graph MLP: h0(99)->128->64->64->emb(32)->out(1) ------
__global__ __launch_bounds__(128) void k_mlp(
    const float* __restrict__ h0,
    const float* __restrict__ W1, const float* __restrict__ b1,
    const float* __restrict__ W2, const float* __restrict__ b2,
    const float* __restrict__ W3, const float* __restrict__ b3,
    const float* __restrict__ We, const float* __restrict__ be,
    const float* __restrict__ Wc, const float* __restrict__ bc,
    float* __restrict__ emb, float* __restrict__ outp) {
    __shared__ float s0[99], s1[128], s2[64], s3[64], s4[32];
    int g = blockIdx.x;
    int t = threadIdx.x;
    if (t < 99) s0[t] = h0[g * 99 + t];
    __syncthreads();
    {
        float a = b1[t];
        for (int k = 0; k < 99; ++k) a += s0[k] * W1[k * 128 + t];
        s1[t] = lrelu(a);
    }
    __syncthreads();
    if (t < 64) {
        float a = b2[t];
        for (int k = 0; k < 128; ++k) a += s1[k] * W2[k * 64 + t];
        s2[t] = lrelu(a);
    }
    __syncthreads();
    if (t < 64) {
        float a = b3[t];
        for (int k = 0; k < 64; ++k) a += s2[k] * W3[k * 64 + t];
        s3[t] = a;
    }
    __syncthreads();
    if (t < 32) {
        float a = be[t];
        for (int k = 0; k < 64; ++k) a += s3[k] * We[k * 32 + t];
        s4[t] = a;
        emb[g * 32 + t] = a;
    }
    __syncthreads();
    if (t == 0) {
        float a = bc[0];
        for (int k = 0; k < 32; ++k) a += s4[k] * Wc[k];
        outp[g] = a;
    }
}

// ---------------- host ----------------
extern "C" void kernel_launch(void* const* d_in, const int* in_sizes, int n_in,
                              void* d_out, int out_size, void* d_ws, size_t ws_size,
                              hipStream_t stream) {
    const float* x   = (const float*)d_in[0];
    const float* W1  = (const float*)d_in[1];
    const float* b1  = (const float*)d_in[2];
    const float* W2  = (const float*)d_in[3];
    const float* b2  = (const float*)d_in[4];
    const float* W3  = (const float*)d_in[5];
    const float* b3  = (const float*)d_in[6];
    const float* We  = (const float*)d_in[7];
    const float* be  = (const float*)d_in[8];
    const float* Wc  = (const float*)d_in[9];
    const float* bc  = (const float*)d_in[10];
    const int*   eix = (const int*)d_in[11];
    const int*   batch = (const int*)d_in[12];
    const int* esrc = eix;
    const int* edst = eix + N_EDGES;

    char* ws = (char*)d_ws;
    size_t off = 0;
    auto alloc = [&](size_t bytes) -> void* {
        void* p = ws + off;
        off = (off + bytes + 255) & ~(size_t)255;
        return p;
    };
    int*   counts  = (int*)alloc((size_t)N_NODES * 4);
    int*   offsets = (int*)alloc((size_t)(N_NODES + 1) * 4);
    int*   cursor  = (int*)alloc((size_t)N_NODES * 4);
    float* dinv    = (float*)alloc((size_t)N_NODES * 4);
    float* dinv2   = (float*)alloc((size_t)N_NODES * 4);
    float* sdeg    = (float*)alloc((size_t)N_NODES * 4);
    int*   bsums   = (int*)alloc(1024 * 4);
    int*   gcur    = (int*)alloc(NPART * 4);
    uint2* gbuf    = (uint2*)alloc((size_t)NPART * BCAP * 8);
    int*   csr_src = (int*)alloc((size_t)N_EDGES * 4);
    float4* v0     = (float4*)alloc((size_t)N_NODES * 16);
    float4* p1[7];
    for (int i = 0; i < 7; ++i) p1[i] = (float4*)alloc((size_t)N_NODES * 16);
    float* s1v = (float*)alloc((size_t)N_NODES * 12 * 4);
    float* p2[7];
    for (int i = 0; i < 7; ++i) p2[i] = (float*)alloc((size_t)N_NODES * 12 * 4);
    float* feats = (float*)alloc((size_t)N_NODES * 33 * 4);
    float* meanb = (float*)alloc((size_t)NG * 33 * 4);
    float* h0 = (float*)alloc((size_t)NG * 99 * 4);
    (void)ws_size; (void)in_sizes; (void)n_in; (void)out_size;

    const int TB = 256;
    const int gbN = (N_NODES + TB - 1) / TB;
    const int nbScan = (N_NODES + 1023) / 1024;

    // --- CSR build: bin -> count(LDS hist) -> scan -> scatter(bucket-local) ---
    hipLaunchKernelGGL(k_zero_i32, dim3(gbN), dim3(TB), 0, stream, counts, N_NODES);
    hipLaunchKernelGGL(k_zero_i32, dim3(1), dim3(TB), 0, stream, gcur, NPART);
    hipLaunchKernelGGL(k_bin, dim3(NBBLK), dim3(TB), 0, stream, esrc, edst, gcur, gbuf);
    hipLaunchKernelGGL(k_count_b, dim3(64), dim3(1024), 0, stream, gcur, gbuf, counts);
    hipLaunchKernelGGL(k_dinv, dim3(gbN), dim3(TB), 0, stream, counts, dinv, dinv2, sdeg);
    hipLaunchKernelGGL(k_scan_block, dim3(nbScan), dim3(1024), 0, stream, counts, offsets, bsums, N_NODES);
    hipLaunchKernelGGL(k_scan_bsums, dim3(1), dim3(1), 0, stream, bsums, nbScan);
    hipLaunchKernelGGL(k_scan_add, dim3(nbScan), dim3(1024), 0, stream, offsets, bsums, N_NODES);
    hipLaunchKernelGGL(k_copy_i32, dim3(gbN), dim3(TB), 0, stream, offsets, cursor, N_NODES);
    hipLaunchKernelGGL(k_scatter_b, dim3(128), dim3(TB), 0, stream, gcur, gbuf, cursor, csr_src);

    // --- v-space init (float4-padded) ---
    hipLaunchKernelGGL(k_vinit, dim3(gbN), dim3(TB), 0, stream, x, dinv, v0);

    const int saveT[5] = {1, 2, 4, 8, 16};

    // --- pass 1: diffuse (N,3) in v-space, save levels 1,2,4,8,16 ---
    const float4* prev = v0;
    float4* saves1[5];
    {
        int si = 0, sc = 0;
        const int gb = (N_NODES * 8 + TB - 1) / TB;
        for (int t = 1; t <= 16; ++t) {
            float4* outb;
            if (si < 5 && t == saveT[si]) { outb = p1[si]; saves1[si] = outb; ++si; }
            else { outb = p1[5 + sc]; sc ^= 1; }
            hipLaunchKernelGGL(k_vdiff3, dim3(gb), dim3(TB), 0, stream,
                               prev, outb, offsets, csr_src, dinv2);
            prev = outb;
        }
    }
    hipLaunchKernelGGL(k_s1v, dim3(gbN), dim3(TB), 0, stream,
                       saves1[0], saves1[1], saves1[2], saves1[3], saves1[4], s1v);

    // --- pass 2: diffuse (N,12) in v-space, save levels 1,2,4,8,16 ---
    float* saves2[5];
    {
        const float* prev2 = s1v;  // v2_0 = |v-differences| = s1v (dinv factors cancel)
        int si = 0, sc = 0;
        const int gb = (N_NODES * 12 + TB - 1) / TB;
        for (int t = 1; t <= 16; ++t) {
            float* outb;
            if (si < 5 && t == saveT[si]) { outb = p2[si]; saves2[si] = outb; ++si; }
            else { outb = p2[5 + sc]; sc ^= 1; }
            hipLaunchKernelGGL(k_vdiff12, dim3(gb), dim3(TB), 0, stream,
                               (const float4*)prev2, (float4*)outb, offsets, csr_src, dinv2);
            prev2 = outb;
        }
    }

    // --- features + moments ---
    hipLaunchKernelGGL(k_feats, dim3(gbN), dim3(TB), 0, stream,
                       x, s1v, saves2[0], saves2[1], saves2[2], saves2[3], saves2[4], sdeg, feats);
    hipLaunchKernelGGL(k_moments_mean, dim3(NG), dim3(256), 0, stream, feats, batch, meanb);
    hipLaunchKernelGGL(k_moments_vs, dim3(NG), dim3(256), 0, stream, feats, batch, meanb, h0);

    // --- fused MLP head ---
    float* emb  = (float*)d_out;            // (512,32)
    float* outp = (float*)d_out + NG * 32;  // (512,1)
    hipLaunchKernelGGL(k_mlp, dim3(NG), dim3(128), 0, stream,
                       h0, W1, b1, W2, b2, W3, b3, We, be, Wc, bc, emb, outp);
}

// Round 10
// 809.351 us; speedup vs baseline: 1.0468x; 1.0468x over previous
//
#include <hip/hip_runtime.h>

// ---------------- problem constants (fixed by reference) ----------------
#define N_NODES 100000
#define N_EDGES 1600000
#define NG      512
#define NPART   8          // dst partitions (bucket radix)
#define NPP     12500      // nodes per partition
#define BCAP    245760     // per-bucket capacity (entries; expected ~200K)
#define BQ      1024       // LDS staging entries per bucket
#define BFLUSH  512        // flush chunk
#define NBBLK   256        // k_bin blocks
#define EPB     ((N_EDGES + NBBLK - 1) / NBBLK)   // 6250 edges per bin-block
#define SCAT_SLICES 128    // scatter slices per partition -> 1024 blocks

static __device__ __forceinline__ float lrelu(float v) {
    return v >= 0.0f ? v : 0.01f * v;
}

// ---------------- tiny setup kernels ----------------
__global__ void k_zero_i32(int* __restrict__ p, int n) {
    int i = blockIdx.x * blockDim.x + threadIdx.x;
    if (i < n) p[i] = 0;
}

__global__ void k_copy_i32(const int* __restrict__ s, int* __restrict__ d, int n) {
    int i = blockIdx.x * blockDim.x + threadIdx.x;
    if (i < n) d[i] = s[i];
}

// dinv = 1/sqrt(deg+1); dinv2 = 1/(deg+1); sdeg = sqrt(deg+1)
__global__ void k_dinv(const int* __restrict__ counts, float* __restrict__ dinv,
                       float* __restrict__ dinv2, float* __restrict__ sdeg) {
    int i = blockIdx.x * blockDim.x + threadIdx.x;
    if (i < N_NODES) {
        float deg = (float)(counts[i] + 1);
        float s = sqrtf(deg);
        sdeg[i] = s;
        dinv[i] = 1.0f / s;
        dinv2[i] = 1.0f / deg;
    }
}

// ---------------- phase A: bin edges into 8 dst-partition buckets ----------------
__global__ __launch_bounds__(256) void k_bin(const int* __restrict__ esrc,
                                             const int* __restrict__ edst,
                                             int* __restrict__ gcur,
                                             uint2* __restrict__ gbuf) {
    __shared__ uint2 buf[NPART][BQ];
    __shared__ int lcnt[NPART];
    __shared__ int gbase[NPART];
    if (threadIdx.x < NPART) lcnt[threadIdx.x] = 0;
    __syncthreads();
    int base = blockIdx.x * EPB;
    int end = base + EPB; if (end > N_EDGES) end = N_EDGES;
    for (int r = base; r < end; r += 2048) {
        int rend = r + 2048; if (rend > end) rend = end;
        for (int e = r + (int)threadIdx.x; e < rend; e += 256) {
            int d = edst[e];
            int s = esrc[e];
            int b = d / NPP;                      // 0..7
            int pos = atomicAdd(&lcnt[b], 1);
            if (pos < BQ) {
                buf[b][pos] = make_uint2((unsigned)s, (unsigned)d);
            } else {                              // safety overflow path
                int g = atomicAdd(&gcur[b], 1);
                gbuf[(size_t)b * BCAP + g] = make_uint2((unsigned)s, (unsigned)d);
            }
        }
        __syncthreads();
        for (int b = 0; b < NPART; ++b) {
            int cnt = lcnt[b];
            if (cnt >= BFLUSH) {
                if (threadIdx.x == 0) gbase[b] = atomicAdd(&gcur[b], BFLUSH);
                __syncthreads();
                int gb = gbase[b];
                for (int i = threadIdx.x; i < BFLUSH; i += 256)
                    gbuf[(size_t)b * BCAP + gb + i] = buf[b][i];
                __syncthreads();
                int inb = cnt < BQ ? cnt : BQ;
                int rem = inb - BFLUSH;           // <= 512: disjoint regions
                for (int i = threadIdx.x; i < rem; i += 256)
                    buf[b][i] = buf[b][BFLUSH + i];
                __syncthreads();
                if (threadIdx.x == 0) lcnt[b] = rem;
                __syncthreads();
            }
        }
    }
    for (int b = 0; b < NPART; ++b) {
        int cnt = lcnt[b]; if (cnt > BQ) cnt = BQ;
        if (cnt > 0) {
            if (threadIdx.x == 0) gbase[b] = atomicAdd(&gcur[b], cnt);
            __syncthreads();
            int gb = gbase[b];
            for (int i = threadIdx.x; i < cnt; i += 256)
                gbuf[(size_t)b * BCAP + gb + i] = buf[b][i];
        }
        __syncthreads();
    }
}

// ---------------- phase B1: per-partition degree count via LDS histogram ---------
__global__ __launch_bounds__(1024) void k_count_b(const int* __restrict__ gcur,
                                                  const uint2* __restrict__ gbuf,
                                                  int* __restrict__ counts) {
    __shared__ int h[NPP];
    int p = blockIdx.x & (NPART - 1);
    int slice = blockIdx.x >> 3;                  // 0..7
    for (int i = threadIdx.x; i < NPP; i += 1024) h[i] = 0;
    __syncthreads();
    int n = gcur[p];
    int per = (n + 7) / 8;
    int lo = slice * per, hi = lo + per; if (hi > n) hi = n;
    const uint2* bb = gbuf + (size_t)p * BCAP;
    int pl = p * NPP;
    for (int i = lo + (int)threadIdx.x; i < hi; i += 1024) {
        int d = (int)bb[i].y - pl;
        atomicAdd(&h[d], 1);
    }
    __syncthreads();
    for (int i = threadIdx.x; i < NPP; i += 1024)
        if (h[i]) atomicAdd(&counts[pl + i], h[i]);
}

// ---------------- exclusive scan (counts -> offsets) ----------------
__global__ void k_scan_block(const int* __restrict__ counts, int* __restrict__ offsets,
                             int* __restrict__ bsums, int n) {
    __shared__ int tmp[1024];
    int gid = blockIdx.x * 1024 + threadIdx.x;
    int v = (gid < n) ? counts[gid] : 0;
    tmp[threadIdx.x] = v;
    __syncthreads();
    for (int off = 1; off < 1024; off <<= 1) {
        int t = (threadIdx.x >= off) ? tmp[threadIdx.x - off] : 0;
        __syncthreads();
        tmp[threadIdx.x] += t;
        __syncthreads();
    }
    if (gid < n) offsets[gid + 1] = tmp[threadIdx.x];
    if (threadIdx.x == 1023) bsums[blockIdx.x] = tmp[1023];
}

__global__ void k_scan_bsums(int* __restrict__ bsums, int nb) {
    if (blockIdx.x == 0 && threadIdx.x == 0) {
        int acc = 0;
        for (int b = 0; b < nb; ++b) { int v = bsums[b]; bsums[b] = acc; acc += v; }
    }
}

__global__ void k_scan_add(int* __restrict__ offsets, const int* __restrict__ bsums, int n) {
    int gid = blockIdx.x * 1024 + threadIdx.x;
    if (gid < n) offsets[gid + 1] += bsums[blockIdx.x];
    if (gid == 0) offsets[0] = 0;
}

// ---------------- phase B2: per-partition CSR scatter, 1024 blocks ---------------
__global__ __launch_bounds__(256) void k_scatter_b(const int* __restrict__ gcur,
                                                   const uint2* __restrict__ gbuf,
                                                   int* __restrict__ cursor,
                                                   int* __restrict__ csr_src) {
    int p = blockIdx.x & (NPART - 1);
    int slice = blockIdx.x >> 3;                  // 0..SCAT_SLICES-1
    int n = gcur[p];
    int per = (n + SCAT_SLICES - 1) / SCAT_SLICES;
    int lo = slice * per, hi = lo + per; if (hi > n) hi = n;
    const uint2* bb = gbuf + (size_t)p * BCAP;
    for (int i = lo + (int)threadIdx.x; i < hi; i += 256) {
        uint2 e = bb[i];
        int pos = atomicAdd(&cursor[e.y], 1);
        csr_src[pos] = (int)e.x;
    }
}

// ---------------- v-space init: v = dinv .* x, padded to float4 ----------------
__global__ void k_vinit(const float* __restrict__ x, const float* __restrict__ dinv,
                        float4* __restrict__ v) {
    int i = blockIdx.x * blockDim.x + threadIdx.x;
    if (i >= N_NODES) return;
    float di = dinv[i];
    v[i] = make_float4(di * x[i * 3 + 0], di * x[i * 3 + 1], di * x[i * 3 + 2], 0.0f);
}

// ---------------- diffusion (v-space): v' = 0.5*(v + dinv2*(sum_nbr + v)) --------
// pass 1: float4 node state, 8 edge-split lanes per node -> 800K threads
__global__ __launch_bounds__(256) void k_vdiff3(
    const float4* __restrict__ xin, float4* __restrict__ xout,
    const int* __restrict__ offs, const int* __restrict__ csrc,
    const float* __restrict__ dinv2) {
    int t = blockIdx.x * 256 + threadIdx.x;
    if (t >= N_NODES * 8) return;
    int h = t & 7;
    int i = t >> 3;
    int b = offs[i], e = offs[i + 1];
    float a0 = 0.0f, a1 = 0.0f, a2 = 0.0f;
    for (int p = b + h; p < e; p += 8) {
        int s = csrc[p];
        float4 xv = xin[s];
        a0 += xv.x; a1 += xv.y; a2 += xv.z;
    }
    a0 += __shfl_xor(a0, 1, 64); a1 += __shfl_xor(a1, 1, 64); a2 += __shfl_xor(a2, 1, 64);
    a0 += __shfl_xor(a0, 2, 64); a1 += __shfl_xor(a1, 2, 64); a2 += __shfl_xor(a2, 2, 64);
    a0 += __shfl_xor(a0, 4, 64); a1 += __shfl_xor(a1, 4, 64); a2 += __shfl_xor(a2, 4, 64);
    if (h == 0) {
        float d2 = dinv2[i];
        float4 sv = xin[i];
        xout[i] = make_float4(0.5f * (sv.x + d2 * (a0 + sv.x)),
                              0.5f * (sv.y + d2 * (a1 + sv.y)),
                              0.5f * (sv.z + d2 * (a2 + sv.z)), 0.0f);
    }
}

// pass 2: 12 channels per thread, 8 edge-split lanes per node -> 800K threads
// (1 index load + 3 float4 loads per edge = 4 loads/edge, the minimum)
__global__ __launch_bounds__(256) void k_vdiff12(
    const float4* __restrict__ xin, float4* __restrict__ xout,
    const int* __restrict__ offs, const int* __restrict__ csrc,
    const float* __restrict__ dinv2) {
    int t = blockIdx.x * 256 + threadIdx.x;
    if (t >= N_NODES * 8) return;
    int h = t & 7;
    int i = t >> 3;
    int b = offs[i], e = offs[i + 1];
    float a[12];
#pragma unroll
    for (int c = 0; c < 12; ++c) a[c] = 0.0f;
    for (int p = b + h; p < e; p += 8) {
        int s = csrc[p];
        float4 b0 = xin[s * 3 + 0];
        float4 b1 = xin[s * 3 + 1];
        float4 b2 = xin[s * 3 + 2];
        a[0] += b0.x; a[1] += b0.y; a[2]  += b0.z; a[3]  += b0.w;
        a[4] += b1.x; a[5] += b1.y; a[6]  += b1.z; a[7]  += b1.w;
        a[8] += b2.x; a[9] += b2.y; a[10] += b2.z; a[11] += b2.w;
    }
#pragma unroll
    for (int c = 0; c < 12; ++c) {
        a[c] += __shfl_xor(a[c], 1, 64);
        a[c] += __shfl_xor(a[c], 2, 64);
        a[c] += __shfl_xor(a[c], 4, 64);
    }
    if (h == 0) {
        float d2 = dinv2[i];
        float4 s0 = xin[i * 3 + 0], s1 = xin[i * 3 + 1], s2 = xin[i * 3 + 2];
        xout[i * 3 + 0] = make_float4(0.5f * (s0.x + d2 * (a[0] + s0.x)),
                                      0.5f * (s0.y + d2 * (a[1] + s0.y)),
                                      0.5f * (s0.z + d2 * (a[2] + s0.z)),
                                      0.5f * (s0.w + d2 * (a[3] + s0.w)));
        xout[i * 3 + 1] = make_float4(0.5f * (s1.x + d2 * (a[4] + s1.x)),
                                      0.5f * (s1.y + d2 * (a[5] + s1.y)),
                                      0.5f * (s1.z + d2 * (a[6] + s1.z)),
                                      0.5f * (s1.w + d2 * (a[7] + s1.w)));
        xout[i * 3 + 2] = make_float4(0.5f * (s2.x + d2 * (a[8] + s2.x)),
                                      0.5f * (s2.y + d2 * (a[9] + s2.y)),
                                      0.5f * (s2.z + d2 * (a[10] + s2.z)),
                                      0.5f * (s2.w + d2 * (a[11] + s2.w)));
    }
}

// ---------------- s1 in v-space: |vL[f]-vL[f+1]| (float4-padded levels in) -------
__global__ void k_s1v(const float4* __restrict__ L1, const float4* __restrict__ L2,
                      const float4* __restrict__ L4, const float4* __restrict__ L8,
                      const float4* __restrict__ L16, float* __restrict__ s1v) {
    int i = blockIdx.x * blockDim.x + threadIdx.x;
    if (i >= N_NODES) return;
    float4 v[5];
    v[0] = L1[i]; v[1] = L2[i]; v[2] = L4[i]; v[3] = L8[i]; v[4] = L16[i];
    float* out = s1v + (size_t)i * 12;
#pragma unroll
    for (int f = 0; f < 4; ++f) {
        out[0 * 4 + f] = fabsf(v[f].x - v[f + 1].x);
        out[1 * 4 + f] = fabsf(v[f].y - v[f + 1].y);
        out[2 * 4 + f] = fabsf(v[f].z - v[f + 1].z);
    }
}

// ---------------- feats (N,33), converting v-space -> x-space via sdeg -----------
__global__ void k_feats(const float* __restrict__ x, const float* __restrict__ s1v,
                        const float* __restrict__ M1, const float* __restrict__ M2,
                        const float* __restrict__ M4, const float* __restrict__ M8,
                        const float* __restrict__ M16, const float* __restrict__ sdeg,
                        float* __restrict__ feats) {
    int i = blockIdx.x * blockDim.x + threadIdx.x;
    if (i >= N_NODES) return;
    float sd = sdeg[i];
    float* out = feats + (size_t)i * 33;
    out[0] = x[i * 3 + 0];
    out[1] = x[i * 3 + 1];
    out[2] = x[i * 3 + 2];
    for (int r = 1; r <= 4; ++r)
        for (int c = 0; c < 3; ++c)
            out[r * 3 + c] = sd * s1v[(size_t)i * 12 + c * 4 + (r - 1)];
    const float* Ms[5] = {M1, M2, M4, M8, M16};
    const int FENG[6] = {4, 8, 9, 12, 13, 14};
    for (int m = 0; m < 6; ++m) {
        for (int c2 = 0; c2 < 3; ++c2) {
            int idx = c2 * 16 + FENG[m];
            int w = idx / 12, rem = idx % 12, cc = rem / 4, f = rem % 4;
            float v = Ms[w][(size_t)i * 12 + cc * 4 + f] - Ms[w + 1][(size_t)i * 12 + cc * 4 + f];
            out[(5 + m) * 3 + c2] = fabsf(sd * v);
        }
    }
}

// ---------------- per-graph moments, single pass, lane-owns-channel --------------
// raw moments: var = E[x^2]-mu^2 ; skew = E[x^3]-3*mu*E[x^2]+2*mu^3
static __device__ __forceinline__ int lower_bound_i(const int* __restrict__ a, int n, int key) {
    int lo = 0, hi = n;
    while (lo < hi) { int mid = (lo + hi) >> 1; if (a[mid] < key) lo = mid + 1; else hi = mid; }
    return lo;
}

__global__ __launch_bounds__(256) void k_moments(
    const float* __restrict__ feats, const int* __restrict__ batch,
    float* __restrict__ h0) {
    __shared__ float P1[4][33], P2[4][33], P3[4][33];
    int g = blockIdx.x;
    int lo = lower_bound_i(batch, N_NODES, g);
    int hi = lower_bound_i(batch, N_NODES, g + 1);
    int w = threadIdx.x >> 6;      // wave 0..3
    int l = threadIdx.x & 63;      // lane
    float s1 = 0.0f, s2 = 0.0f, s3 = 0.0f;
    if (l < 33) {
        for (int i = lo + w; i < hi; i += 4) {
            float v = feats[(size_t)i * 33 + l];
            s1 += v;
            s2 += v * v;
            s3 += v * v * v;
        }
        P1[w][l] = s1; P2[w][l] = s2; P3[w][l] = s3;
    }
    __syncthreads();
    if (threadIdx.x < 33) {
        int c = threadIdx.x;
        float S1 = P1[0][c] + P1[1][c] + P1[2][c] + P1[3][c];
        float S2 = P2[0][c] + P2[1][c] + P2[2][c] + P2[3][c];
        float S3 = P3[0][c] + P3[1][c] + P3[2][c] + P3[3][c];
        float cnt = (float)((hi - lo) > 1 ? (hi - lo) : 1);
        float mu  = S1 / cnt;
        float ex2 = S2 / cnt;
        float ex3 = S3 / cnt;
        float var = ex2 - mu * mu;
        float skw = ex3 - 3.0f * mu * ex2 + 2.0f * mu * mu * mu;
        h0[g * 99 + c]      = lrelu(mu);
        h0[g * 99 + 33 + c] = lrelu(var);
        h0[g * 99 + 66 + c] = lrelu(skw);
    }
}

// ---------------- fused per-graph MLP: h0(99)->128->64->64->emb(32)->out(1) ------
__global__ __launch_bounds__(128) void k_mlp(
    const float* __restrict__ h0,
    const float* __restrict__ W1, const float* __restrict__ b1,
    const float* __restrict__ W2, const float* __restrict__ b2,
    const float* __restrict__ W3, const float* __restrict__ b3,
    const float* __restrict__ We, const float* __restrict__ be,
    const float* __restrict__ Wc, const float* __restrict__ bc,
    float* __restrict__ emb, float* __restrict__ outp) {
    __shared__ float s0[99], s1[128], s2[64], s3[64], s4[32];
    int g = blockIdx.x;
    int t = threadIdx.x;
    if (t < 99) s0[t] = h0[g * 99 + t];
    __syncthreads();
    {
        float a = b1[t];
        for (int k = 0; k < 99; ++k) a += s0[k] * W1[k * 128 + t];
        s1[t] = lrelu(a);
    }
    __syncthreads();
    if (t < 64) {
        float a = b2[t];
        for (int k = 0; k < 128; ++k) a += s1[k] * W2[k * 64 + t];
        s2[t] = lrelu(a);
    }
    __syncthreads();
    if (t < 64) {
        float a = b3[t];
        for (int k = 0; k < 64; ++k) a += s2[k] * W3[k * 64 + t];
        s3[t] = a;
    }
    __syncthreads();
    if (t < 32) {
        float a = be[t];
        for (int k = 0; k < 64; ++k) a += s3[k] * We[k * 32 + t];
        s4[t] = a;
        emb[g * 32 + t] = a;
    }
    __syncthreads();
    if (t == 0) {
        float a = bc[0];
        for (int k = 0; k < 32; ++k) a += s4[k] * Wc[k];
        outp[g] = a;
    }
}

// ---------------- host ----------------
extern "C" void kernel_launch(void* const* d_in, const int* in_sizes, int n_in,
                              void* d_out, int out_size, void* d_ws, size_t ws_size,
                              hipStream_t stream) {
    const float* x   = (const float*)d_in[0];
    const float* W1  = (const float*)d_in[1];
    const float* b1  = (const float*)d_in[2];
    const float* W2  = (const float*)d_in[3];
    const float* b2  = (const float*)d_in[4];
    const float* W3  = (const float*)d_in[5];
    const float* b3  = (const float*)d_in[6];
    const float* We  = (const float*)d_in[7];
    const float* be  = (const float*)d_in[8];
    const float* Wc  = (const float*)d_in[9];
    const float* bc  = (const float*)d_in[10];
    const int*   eix = (const int*)d_in[11];
    const int*   batch = (const int*)d_in[12];
    const int* esrc = eix;
    const int* edst = eix + N_EDGES;

    char* ws = (char*)d_ws;
    size_t off = 0;
    auto alloc = [&](size_t bytes) -> void* {
        void* p = ws + off;
        off = (off + bytes + 255) & ~(size_t)255;
        return p;
    };
    int*   counts  = (int*)alloc((size_t)N_NODES * 4);
    int*   offsets = (int*)alloc((size_t)(N_NODES + 1) * 4);
    int*   cursor  = (int*)alloc((size_t)N_NODES * 4);
    float* dinv    = (float*)alloc((size_t)N_NODES * 4);
    float* dinv2   = (float*)alloc((size_t)N_NODES * 4);
    float* sdeg    = (float*)alloc((size_t)N_NODES * 4);
    int*   bsums   = (int*)alloc(1024 * 4);
    int*   gcur    = (int*)alloc(NPART * 4);
    uint2* gbuf    = (uint2*)alloc((size_t)NPART * BCAP * 8);
    int*   csr_src = (int*)alloc((size_t)N_EDGES * 4);
    float4* v0     = (float4*)alloc((size_t)N_NODES * 16);
    float4* p1[7];
    for (int i = 0; i < 7; ++i) p1[i] = (float4*)alloc((size_t)N_NODES * 16);
    float* s1v = (float*)alloc((size_t)N_NODES * 12 * 4);
    float* p2[7];
    for (int i = 0; i < 7; ++i) p2[i] = (float*)alloc((size_t)N_NODES * 12 * 4);
    float* feats = (float*)alloc((size_t)N_NODES * 33 * 4);
    float* h0 = (float*)alloc((size_t)NG * 99 * 4);
    (void)ws_size; (void)in_sizes; (void)n_in; (void)out_size;

    const int TB = 256;
    const int gbN = (N_NODES + TB - 1) / TB;
    const int nbScan = (N_NODES + 1023) / 1024;

    // --- CSR build: bin -> count(LDS hist) -> scan -> scatter(1024 blocks) ---
    hipLaunchKernelGGL(k_zero_i32, dim3(gbN), dim3(TB), 0, stream, counts, N_NODES);
    hipLaunchKernelGGL(k_zero_i32, dim3(1), dim3(TB), 0, stream, gcur, NPART);
    hipLaunchKernelGGL(k_bin, dim3(NBBLK), dim3(TB), 0, stream, esrc, edst, gcur, gbuf);
    hipLaunchKernelGGL(k_count_b, dim3(64), dim3(1024), 0, stream, gcur, gbuf, counts);
    hipLaunchKernelGGL(k_dinv, dim3(gbN), dim3(TB), 0, stream, counts, dinv, dinv2, sdeg);
    hipLaunchKernelGGL(k_scan_block, dim3(nbScan), dim3(1024), 0, stream, counts, offsets, bsums, N_NODES);
    hipLaunchKernelGGL(k_scan_bsums, dim3(1), dim3(1), 0, stream, bsums, nbScan);
    hipLaunchKernelGGL(k_scan_add, dim3(nbScan), dim3(1024), 0, stream, offsets, bsums, N_NODES);
    hipLaunchKernelGGL(k_copy_i32, dim3(gbN), dim3(TB), 0, stream, offsets, cursor, N_NODES);
    hipLaunchKernelGGL(k_scatter_b, dim3(NPART * SCAT_SLICES), dim3(TB), 0, stream,
                       gcur, gbuf, cursor, csr_src);

    // --- v-space init (float4-padded) ---
    hipLaunchKernelGGL(k_vinit, dim3(gbN), dim3(TB), 0, stream, x, dinv, v0);

    const int saveT[5] = {1, 2, 4, 8, 16};

    // --- pass 1: diffuse (N,3) in v-space, save levels 1,2,4,8,16 ---
    const float4* prev = v0;
    float4* saves1[5];
    {
        int si = 0, sc = 0;
        const int gb = (N_NODES * 8 + TB - 1) / TB;
        for (int t = 1; t <= 16; ++t) {
            float4* outb;
            if (si < 5 && t == saveT[si]) { outb = p1[si]; saves1[si] = outb; ++si; }
            else { outb = p1[5 + sc]; sc ^= 1; }
            hipLaunchKernelGGL(k_vdiff3, dim3(gb), dim3(TB), 0, stream,
                               prev, outb, offsets, csr_src, dinv2);
            prev = outb;
        }
    }
    hipLaunchKernelGGL(k_s1v, dim3(gbN), dim3(TB), 0, stream,
                       saves1[0], saves1[1], saves1[2], saves1[3], saves1[4], s1v);

    // --- pass 2: diffuse (N,12) in v-space, save levels 1,2,4,8,16 ---
    float* saves2[5];
    {
        const float* prev2 = s1v;  // v2_0 = |v-differences| = s1v (dinv factors cancel)
        int si = 0, sc = 0;
        const int gb = (N_NODES * 8 + TB - 1) / TB;
        for (int t = 1; t <= 16; ++t) {
            float* outb;
            if (si < 5 && t == saveT[si]) { outb = p2[si]; saves2[si] = outb; ++si; }
            else { outb = p2[5 + sc]; sc ^= 1; }
            hipLaunchKernelGGL(k_vdiff12, dim3(gb), dim3(TB), 0, stream,
                               (const float4*)prev2, (float4*)outb, offsets, csr_src, dinv2);
            prev2 = outb;
        }
    }

    // --- features + single-pass moments ---
    hipLaunchKernelGGL(k_feats, dim3(gbN), dim3(TB), 0, stream,
                       x, s1v, saves2[0], saves2[1], saves2[2], saves2[3], saves2[4], sdeg, feats);
    hipLaunchKernelGGL(k_moments, dim3(NG), dim3(256), 0, stream, feats, batch, h0);

    // --- fused MLP head ---
    float* emb  = (float*)d_out;            // (512,32)
    float* outp = (float*)d_out + NG * 32;  // (512,1)
    hipLaunchKernelGGL(k_mlp, dim3(NG), dim3(128), 0, stream,
                       h0, W1, b1, W2, b2, W3, b3, We, be, Wc, bc, emb, outp);
}

// Round 11
// 746.821 us; speedup vs baseline: 1.1344x; 1.0837x over previous
//
#include <hip/hip_runtime.h>

// ---------------- problem constants (fixed by reference) ----------------
#define N_NODES 100000
#define N_EDGES 1600000
#define NG      512
// sub-bucket radix CSR build
#define NSB     98          // sub-buckets of 1024 dst nodes (d >> 10)
#define SUBR    1024
#define SCAP    20480       // global per-sub-bucket capacity (avg 16327, +32 sigma)
#define SD      96          // LDS staging depth per bucket in k_bin2 (avg fill 64)
#define B2BLK   256         // k_bin2 blocks
#define B2E     ((N_EDGES + B2BLK - 1) / B2BLK)   // 6250 edges per bin2 block
#define PCAP    18432       // k_place LDS staging entries (avg 16327, +16 sigma)

static __device__ __forceinline__ float lrelu(float v) {
    return v >= 0.0f ? v : 0.01f * v;
}

// ---------------- tiny setup kernels ----------------
__global__ void k_zero_i32(int* __restrict__ p, int n) {
    int i = blockIdx.x * blockDim.x + threadIdx.x;
    if (i < n) p[i] = 0;
}

// dinv = 1/sqrt(deg+1); dinv2 = 1/(deg+1); sdeg = sqrt(deg+1)
__global__ void k_dinv(const int* __restrict__ counts, float* __restrict__ dinv,
                       float* __restrict__ dinv2, float* __restrict__ sdeg) {
    int i = blockIdx.x * blockDim.x + threadIdx.x;
    if (i < N_NODES) {
        float deg = (float)(counts[i] + 1);
        float s = sqrtf(deg);
        sdeg[i] = s;
        dinv[i] = 1.0f / s;
        dinv2[i] = 1.0f / deg;
    }
}

// ---------------- phase A: bin edges into 98 dst sub-buckets (1024 nodes) --------
// LDS-staged; drain coalesced. Overflow path (rare) goes straight to global.
__global__ __launch_bounds__(256) void k_bin2(const int* __restrict__ esrc,
                                              const int* __restrict__ edst,
                                              int* __restrict__ gcur,
                                              uint2* __restrict__ gbuf) {
    __shared__ uint2 st[NSB][SD];
    __shared__ int lcnt[NSB];
    __shared__ int gbase[NSB];
    for (int i = threadIdx.x; i < NSB; i += 256) lcnt[i] = 0;
    __syncthreads();
    int base = blockIdx.x * B2E;
    int end = base + B2E; if (end > N_EDGES) end = N_EDGES;
    for (int e = base + (int)threadIdx.x; e < end; e += 256) {
        int d = edst[e];
        int s = esrc[e];
        int b = d >> 10;                          // 0..97
        int pos = atomicAdd(&lcnt[b], 1);
        if (pos < SD) {
            st[b][pos] = make_uint2((unsigned)s, (unsigned)d);
        } else {                                  // rare overflow
            int g = atomicAdd(&gcur[b], 1);
            gbuf[(size_t)b * SCAP + g] = make_uint2((unsigned)s, (unsigned)d);
        }
    }
    __syncthreads();
    if (threadIdx.x < NSB) {
        int c = lcnt[threadIdx.x]; if (c > SD) c = SD;
        gbase[threadIdx.x] = atomicAdd(&gcur[threadIdx.x], c);
    }
    __syncthreads();
    for (int b = 0; b < NSB; ++b) {
        int cnt = lcnt[b]; if (cnt > SD) cnt = SD;
        int gb = gbase[b];
        for (int i = threadIdx.x; i < cnt; i += 256)
            gbuf[(size_t)b * SCAP + gb + i] = st[b][i];
    }
}

// ---------------- phase B1: per-sub-bucket degree count (LDS hist, coalesced out)
__global__ __launch_bounds__(256) void k_count_s(const int* __restrict__ gcur,
                                                 const uint2* __restrict__ gbuf,
                                                 int* __restrict__ counts) {
    __shared__ int h[SUBR];
    int sb = blockIdx.x;
    int lo = sb * SUBR;
    int nr = N_NODES - lo; if (nr > SUBR) nr = SUBR;
    for (int i = threadIdx.x; i < nr; i += 256) h[i] = 0;
    __syncthreads();
    int n = gcur[sb];
    const uint2* bb = gbuf + (size_t)sb * SCAP;
    for (int i = threadIdx.x; i < n; i += 256)
        atomicAdd(&h[(int)bb[i].y - lo], 1);
    __syncthreads();
    for (int i = threadIdx.x; i < nr; i += 256)
        counts[lo + i] = h[i];
}

// ---------------- exclusive scan (counts -> offsets) ----------------
__global__ void k_scan_block(const int* __restrict__ counts, int* __restrict__ offsets,
                             int* __restrict__ bsums, int n) {
    __shared__ int tmp[1024];
    int gid = blockIdx.x * 1024 + threadIdx.x;
    int v = (gid < n) ? counts[gid] : 0;
    tmp[threadIdx.x] = v;
    __syncthreads();
    for (int off = 1; off < 1024; off <<= 1) {
        int t = (threadIdx.x >= off) ? tmp[threadIdx.x - off] : 0;
        __syncthreads();
        tmp[threadIdx.x] += t;
        __syncthreads();
    }
    if (gid < n) offsets[gid + 1] = tmp[threadIdx.x];
    if (threadIdx.x == 1023) bsums[blockIdx.x] = tmp[1023];
}

__global__ void k_scan_bsums(int* __restrict__ bsums, int nb) {
    if (blockIdx.x == 0 && threadIdx.x == 0) {
        int acc = 0;
        for (int b = 0; b < nb; ++b) { int v = bsums[b]; bsums[b] = acc; acc += v; }
    }
}

__global__ void k_scan_add(int* __restrict__ offsets, const int* __restrict__ bsums, int n) {
    int gid = blockIdx.x * 1024 + threadIdx.x;
    if (gid < n) offsets[gid + 1] += bsums[blockIdx.x];
    if (gid == 0) offsets[0] = 0;
}

// ---------------- phase B2: LDS counting-sort placement, fully coalesced output --
__global__ __launch_bounds__(256) void k_place(const int* __restrict__ gcur,
                                               const uint2* __restrict__ gbuf,
                                               const int* __restrict__ offsets,
                                               int* __restrict__ csr_src) {
    __shared__ int cur[SUBR];
    __shared__ int stage[PCAP];
    int sb = blockIdx.x;
    int lo = sb * SUBR;
    int nr = N_NODES - lo; if (nr > SUBR) nr = SUBR;
    int base = offsets[lo];
    int total = offsets[lo + nr] - base;
    for (int i = threadIdx.x; i < nr; i += 256)
        cur[i] = offsets[lo + i] - base;          // local cursor within sub-range
    __syncthreads();
    int n = gcur[sb];
    const uint2* bb = gbuf + (size_t)sb * SCAP;
    for (int i = threadIdx.x; i < n; i += 256) {
        uint2 e = bb[i];
        int p = atomicAdd(&cur[(int)e.y - lo], 1);
        if (p < PCAP) stage[p] = (int)e.x;
        else csr_src[base + p] = (int)e.x;        // overflow safety (pathological)
    }
    __syncthreads();
    int wtot = total < PCAP ? total : PCAP;
    for (int i = threadIdx.x; i < wtot; i += 256)
        csr_src[base + i] = stage[i];             // single coalesced stream out
}

// ---------------- v-space init: v = dinv .* x, padded to float4 ----------------
__global__ void k_vinit(const float* __restrict__ x, const float* __restrict__ dinv,
                        float4* __restrict__ v) {
    int i = blockIdx.x * blockDim.x + threadIdx.x;
    if (i >= N_NODES) return;
    float di = dinv[i];
    v[i] = make_float4(di * x[i * 3 + 0], di * x[i * 3 + 1], di * x[i * 3 + 2], 0.0f);
}

// ---------------- diffusion (v-space): v' = 0.5*(v + dinv2*(sum_nbr + v)) --------
// pass 1: float4 node state, 8 edge-split lanes per node -> 800K threads
__global__ __launch_bounds__(256) void k_vdiff3(
    const float4* __restrict__ xin, float4* __restrict__ xout,
    const int* __restrict__ offs, const int* __restrict__ csrc,
    const float* __restrict__ dinv2) {
    int t = blockIdx.x * 256 + threadIdx.x;
    if (t >= N_NODES * 8) return;
    int h = t & 7;
    int i = t >> 3;
    int b = offs[i], e = offs[i + 1];
    float a0 = 0.0f, a1 = 0.0f, a2 = 0.0f;
    for (int p = b + h; p < e; p += 8) {
        int s = csrc[p];
        float4 xv = xin[s];
        a0 += xv.x; a1 += xv.y; a2 += xv.z;
    }
    a0 += __shfl_xor(a0, 1, 64); a1 += __shfl_xor(a1, 1, 64); a2 += __shfl_xor(a2, 1, 64);
    a0 += __shfl_xor(a0, 2, 64); a1 += __shfl_xor(a1, 2, 64); a2 += __shfl_xor(a2, 2, 64);
    a0 += __shfl_xor(a0, 4, 64); a1 += __shfl_xor(a1, 4, 64); a2 += __shfl_xor(a2, 4, 64);
    if (h == 0) {
        float d2 = dinv2[i];
        float4 sv = xin[i];
        xout[i] = make_float4(0.5f * (sv.x + d2 * (a0 + sv.x)),
                              0.5f * (sv.y + d2 * (a1 + sv.y)),
                              0.5f * (sv.z + d2 * (a2 + sv.z)), 0.0f);
    }
}

// pass 2: 12 channels/thread, 8 edge-split lanes per node; node state padded to
// 64B (4 float4, quad 3 unused) so each gather touches exactly ONE cache line
__global__ __launch_bounds__(256) void k_vdiff12(
    const float4* __restrict__ xin, float4* __restrict__ xout,
    const int* __restrict__ offs, const int* __restrict__ csrc,
    const float* __restrict__ dinv2) {
    int t = blockIdx.x * 256 + threadIdx.x;
    if (t >= N_NODES * 8) return;
    int h = t & 7;
    int i = t >> 3;
    int b = offs[i], e = offs[i + 1];
    float a[12];
#pragma unroll
    for (int c = 0; c < 12; ++c) a[c] = 0.0f;
    for (int p = b + h; p < e; p += 8) {
        int s = csrc[p];
        float4 b0 = xin[s * 4 + 0];
        float4 b1 = xin[s * 4 + 1];
        float4 b2 = xin[s * 4 + 2];
        a[0] += b0.x; a[1] += b0.y; a[2]  += b0.z; a[3]  += b0.w;
        a[4] += b1.x; a[5] += b1.y; a[6]  += b1.z; a[7]  += b1.w;
        a[8] += b2.x; a[9] += b2.y; a[10] += b2.z; a[11] += b2.w;
    }
#pragma unroll
    for (int c = 0; c < 12; ++c) {
        a[c] += __shfl_xor(a[c], 1, 64);
        a[c] += __shfl_xor(a[c], 2, 64);
        a[c] += __shfl_xor(a[c], 4, 64);
    }
    if (h == 0) {
        float d2 = dinv2[i];
        float4 s0 = xin[i * 4 + 0], s1 = xin[i * 4 + 1], s2 = xin[i * 4 + 2];
        xout[i * 4 + 0] = make_float4(0.5f * (s0.x + d2 * (a[0] + s0.x)),
                                      0.5f * (s0.y + d2 * (a[1] + s0.y)),
                                      0.5f * (s0.z + d2 * (a[2] + s0.z)),
                                      0.5f * (s0.w + d2 * (a[3] + s0.w)));
        xout[i * 4 + 1] = make_float4(0.5f * (s1.x + d2 * (a[4] + s1.x)),
                                      0.5f * (s1.y + d2 * (a[5] + s1.y)),
                                      0.5f * (s1.z + d2 * (a[6] + s1.z)),
                                      0.5f * (s1.w + d2 * (a[7] + s1.w)));
        xout[i * 4 + 2] = make_float4(0.5f * (s2.x + d2 * (a[8] + s2.x)),
                                      0.5f * (s2.y + d2 * (a[9] + s2.y)),
                                      0.5f * (s2.z + d2 * (a[10] + s2.z)),
                                      0.5f * (s2.w + d2 * (a[11] + s2.w)));
    }
}

// ---------------- s1 in v-space, written 64B-padded ([N][16] floats) -------------
__global__ void k_s1v(const float4* __restrict__ L1, const float4* __restrict__ L2,
                      const float4* __restrict__ L4, const float4* __restrict__ L8,
                      const float4* __restrict__ L16, float* __restrict__ s1vp) {
    int i = blockIdx.x * blockDim.x + threadIdx.x;
    if (i >= N_NODES) return;
    float4 v[5];
    v[0] = L1[i]; v[1] = L2[i]; v[2] = L4[i]; v[3] = L8[i]; v[4] = L16[i];
    float* out = s1vp + (size_t)i * 16;
#pragma unroll
    for (int f = 0; f < 4; ++f) {
        out[0 * 4 + f] = fabsf(v[f].x - v[f + 1].x);
        out[1 * 4 + f] = fabsf(v[f].y - v[f + 1].y);
        out[2 * 4 + f] = fabsf(v[f].z - v[f + 1].z);
    }
}

// ---------------- feats (N,33); padded (stride-16) inputs ------------------------
__global__ void k_feats(const float* __restrict__ x, const float* __restrict__ s1vp,
                        const float* __restrict__ M1, const float* __restrict__ M2,
                        const float* __restrict__ M4, const float* __restrict__ M8,
                        const float* __restrict__ M16, const float* __restrict__ sdeg,
                        float* __restrict__ feats) {
    int i = blockIdx.x * blockDim.x + threadIdx.x;
    if (i >= N_NODES) return;
    float sd = sdeg[i];
    float* out = feats + (size_t)i * 33;
    out[0] = x[i * 3 + 0];
    out[1] = x[i * 3 + 1];
    out[2] = x[i * 3 + 2];
    for (int r = 1; r <= 4; ++r)
        for (int c = 0; c < 3; ++c)
            out[r * 3 + c] = sd * s1vp[(size_t)i * 16 + c * 4 + (r - 1)];
    const float* Ms[5] = {M1, M2, M4, M8, M16};
    const int FENG[6] = {4, 8, 9, 12, 13, 14};
    for (int m = 0; m < 6; ++m) {
        for (int c2 = 0; c2 < 3; ++c2) {
            int idx = c2 * 16 + FENG[m];
            int w = idx / 12, rem = idx % 12, cc = rem / 4, f = rem % 4;
            float v = Ms[w][(size_t)i * 16 + cc * 4 + f] - Ms[w + 1][(size_t)i * 16 + cc * 4 + f];
            out[(5 + m) * 3 + c2] = fabsf(sd * v);
        }
    }
}

// ---------------- per-graph moments, single pass, lane-owns-channel --------------
static __device__ __forceinline__ int lower_bound_i(const int* __restrict__ a, int n, int key) {
    int lo = 0, hi = n;
    while (lo < hi) { int mid = (lo + hi) >> 1; if (a[mid] < key) lo = mid + 1; else hi = mid; }
    return lo;
}

__global__ __launch_bounds__(256) void k_moments(
    const float* __restrict__ feats, const int* __restrict__ batch,
    float* __restrict__ h0) {
    __shared__ float P1[4][33], P2[4][33], P3[4][33];
    int g = blockIdx.x;
    int lo = lower_bound_i(batch, N_NODES, g);
    int hi = lower_bound_i(batch, N_NODES, g + 1);
    int w = threadIdx.x >> 6;      // wave 0..3
    int l = threadIdx.x & 63;      // lane
    float s1 = 0.0f, s2 = 0.0f, s3 = 0.0f;
    if (l < 33) {
        for (int i = lo + w; i < hi; i += 4) {
            float v = feats[(size_t)i * 33 + l];
            s1 += v;
            s2 += v * v;
            s3 += v * v * v;
        }
        P1[w][l] = s1; P2[w][l] = s2; P3[w][l] = s3;
    }
    __syncthreads();
    if (threadIdx.x < 33) {
        int c = threadIdx.x;
        float S1 = P1[0][c] + P1[1][c] + P1[2][c] + P1[3][c];
        float S2 = P2[0][c] + P2[1][c] + P2[2][c] + P2[3][c];
        float S3 = P3[0][c] + P3[1][c] + P3[2][c] + P3[3][c];
        float cnt = (float)((hi - lo) > 1 ? (hi - lo) : 1);
        float mu  = S1 / cnt;
        float ex2 = S2 / cnt;
        float ex3 = S3 / cnt;
        float var = ex2 - mu * mu;
        float skw = ex3 - 3.0f * mu * ex2 + 2.0f * mu * mu * mu;
        h0[g * 99 + c]      = lrelu(mu);
        h0[g * 99 + 33 + c] = lrelu(var);
        h0[g * 99 + 66 + c] = lrelu(skw);
    }
}

// ---------------- fused per-graph MLP: h0(99)->128->64->64->emb(32)->out(1) ------
__global__ __launch_bounds__(128) void k_mlp(
    const float* __restrict__ h0,
    const float* __restrict__ W1, const float* __restrict__ b1,
    const float* __restrict__ W2, const float* __restrict__ b2,
    const float* __restrict__ W3, const float* __restrict__ b3,
    const float* __restrict__ We, const float* __restrict__ be,
    const float* __restrict__ Wc, const float* __restrict__ bc,
    float* __restrict__ emb, float* __restrict__ outp) {
    __shared__ float s0[99], s1[128], s2[64], s3[64], s4[32];
    int g = blockIdx.x;
    int t = threadIdx.x;
    if (t < 99) s0[t] = h0[g * 99 + t];
    __syncthreads();
    {
        float a = b1[t];
        for (int k = 0; k < 99; ++k) a += s0[k] * W1[k * 128 + t];
        s1[t] = lrelu(a);
    }
    __syncthreads();
    if (t < 64) {
        float a = b2[t];
        for (int k = 0; k < 128; ++k) a += s1[k] * W2[k * 64 + t];
        s2[t] = lrelu(a);
    }
    __syncthreads();
    if (t < 64) {
        float a = b3[t];
        for (int k = 0; k < 64; ++k) a += s2[k] * W3[k * 64 + t];
        s3[t] = a;
    }
    __syncthreads();
    if (t < 32) {
        float a = be[t];
        for (int k = 0; k < 64; ++k) a += s3[k] * We[k * 32 + t];
        s4[t] = a;
        emb[g * 32 + t] = a;
    }
    __syncthreads();
    if (t == 0) {
        float a = bc[0];
        for (int k = 0; k < 32; ++k) a += s4[k] * Wc[k];
        outp[g] = a;
    }
}

// ---------------- host ----------------
extern "C" void kernel_launch(void* const* d_in, const int* in_sizes, int n_in,
                              void* d_out, int out_size, void* d_ws, size_t ws_size,
                              hipStream_t stream) {
    const float* x   = (const float*)d_in[0];
    const float* W1  = (const float*)d_in[1];
    const float* b1  = (const float*)d_in[2];
    const float* W2  = (const float*)d_in[3];
    const float* b2  = (const float*)d_in[4];
    const float* W3  = (const float*)d_in[5];
    const float* b3  = (const float*)d_in[6];
    const float* We  = (const float*)d_in[7];
    const float* be  = (const float*)d_in[8];
    const float* Wc  = (const float*)d_in[9];
    const float* bc  = (const float*)d_in[10];
    const int*   eix = (const int*)d_in[11];
    const int*   batch = (const int*)d_in[12];
    const int* esrc = eix;
    const int* edst = eix + N_EDGES;

    char* ws = (char*)d_ws;
    size_t off = 0;
    auto alloc = [&](size_t bytes) -> void* {
        void* p = ws + off;
        off = (off + bytes + 255) & ~(size_t)255;
        return p;
    };
    int*   counts  = (int*)alloc((size_t)N_NODES * 4);
    int*   offsets = (int*)alloc((size_t)(N_NODES + 1) * 4);
    float* dinv    = (float*)alloc((size_t)N_NODES * 4);
    float* dinv2   = (float*)alloc((size_t)N_NODES * 4);
    float* sdeg    = (float*)alloc((size_t)N_NODES * 4);
    int*   bsums   = (int*)alloc(1024 * 4);
    int*   gcur    = (int*)alloc(NSB * 4);
    uint2* gbuf    = (uint2*)alloc((size_t)NSB * SCAP * 8);
    int*   csr_src = (int*)alloc((size_t)N_EDGES * 4);
    float4* v0     = (float4*)alloc((size_t)N_NODES * 16);
    float4* p1[7];
    for (int i = 0; i < 7; ++i) p1[i] = (float4*)alloc((size_t)N_NODES * 16);
    float* s1vp = (float*)alloc((size_t)N_NODES * 16 * 4);   // padded [N][16]
    float* p2[7];
    for (int i = 0; i < 7; ++i) p2[i] = (float*)alloc((size_t)N_NODES * 16 * 4);
    float* feats = (float*)alloc((size_t)N_NODES * 33 * 4);
    float* h0 = (float*)alloc((size_t)NG * 99 * 4);
    (void)ws_size; (void)in_sizes; (void)n_in; (void)out_size;

    const int TB = 256;
    const int gbN = (N_NODES + TB - 1) / TB;
    const int nbScan = (N_NODES + 1023) / 1024;

    // --- CSR build: bin2 -> count_s -> scan -> place (all writes coalesced) ---
    hipLaunchKernelGGL(k_zero_i32, dim3(1), dim3(TB), 0, stream, gcur, NSB);
    hipLaunchKernelGGL(k_bin2, dim3(B2BLK), dim3(TB), 0, stream, esrc, edst, gcur, gbuf);
    hipLaunchKernelGGL(k_count_s, dim3(NSB), dim3(TB), 0, stream, gcur, gbuf, counts);
    hipLaunchKernelGGL(k_dinv, dim3(gbN), dim3(TB), 0, stream, counts, dinv, dinv2, sdeg);
    hipLaunchKernelGGL(k_scan_block, dim3(nbScan), dim3(1024), 0, stream, counts, offsets, bsums, N_NODES);
    hipLaunchKernelGGL(k_scan_bsums, dim3(1), dim3(1), 0, stream, bsums, nbScan);
    hipLaunchKernelGGL(k_scan_add, dim3(nbScan), dim3(1024), 0, stream, offsets, bsums, N_NODES);
    hipLaunchKernelGGL(k_place, dim3(NSB), dim3(TB), 0, stream, gcur, gbuf, offsets, csr_src);

    // --- v-space init (float4-padded) ---
    hipLaunchKernelGGL(k_vinit, dim3(gbN), dim3(TB), 0, stream, x, dinv, v0);

    const int saveT[5] = {1, 2, 4, 8, 16};

    // --- pass 1: diffuse (N,3) in v-space, save levels 1,2,4,8,16 ---
    const float4* prev = v0;
    float4* saves1[5];
    {
        int si = 0, sc = 0;
        const int gb = (N_NODES * 8 + TB - 1) / TB;
        for (int t = 1; t <= 16; ++t) {
            float4* outb;
            if (si < 5 && t == saveT[si]) { outb = p1[si]; saves1[si] = outb; ++si; }
            else { outb = p1[5 + sc]; sc ^= 1; }
            hipLaunchKernelGGL(k_vdiff3, dim3(gb), dim3(TB), 0, stream,
                               prev, outb, offsets, csr_src, dinv2);
            prev = outb;
        }
    }
    hipLaunchKernelGGL(k_s1v, dim3(gbN), dim3(TB), 0, stream,
                       saves1[0], saves1[1], saves1[2], saves1[3], saves1[4], s1vp);

    // --- pass 2: diffuse (N,12) in v-space (64B-padded state), save 1,2,4,8,16 ---
    float* saves2[5];
    {
        const float* prev2 = s1vp;  // v2_0 = |v-differences| = s1v (dinv factors cancel)
        int si = 0, sc = 0;
        const int gb = (N_NODES * 8 + TB - 1) / TB;
        for (int t = 1; t <= 16; ++t) {
            float* outb;
            if (si < 5 && t == saveT[si]) { outb = p2[si]; saves2[si] = outb; ++si; }
            else { outb = p2[5 + sc]; sc ^= 1; }
            hipLaunchKernelGGL(k_vdiff12, dim3(gb), dim3(TB), 0, stream,
                               (const float4*)prev2, (float4*)outb, offsets, csr_src, dinv2);
            prev2 = outb;
        }
    }

    // --- features + single-pass moments ---
    hipLaunchKernelGGL(k_feats, dim3(gbN), dim3(TB), 0, stream,
                       x, s1vp, saves2[0], saves2[1], saves2[2], saves2[3], saves2[4], sdeg, feats);
    hipLaunchKernelGGL(k_moments, dim3(NG), dim3(256), 0, stream, feats, batch, h0);

    // --- fused MLP head ---
    float* emb  = (float*)d_out;            // (512,32)
    float* outp = (float*)d_out + NG * 32;  // (512,1)
    hipLaunchKernelGGL(k_mlp, dim3(NG), dim3(128), 0, stream,
                       h0, W1, b1, W2, b2, W3, b3, We, be, Wc, bc, emb, outp);
}